// Round 3
// baseline (730.702 us; speedup 1.0000x reference)
//
#include <hip/hip_runtime.h>
#include <stdint.h>
#include <stddef.h>

#define HEADS 24
#define HD    128
#define BB    2
#define SS    2304
#define DD    3072      // HEADS*HD
#define NN3   9216      // 3*DD
#define MM    4608      // BB*SS

typedef unsigned short ushort_t;
typedef __bf16 bf16x8 __attribute__((ext_vector_type(8)));
typedef float  f32x4  __attribute__((ext_vector_type(4)));

union frag_u { bf16x8 f; uint4 v; unsigned d[4]; };

__device__ __forceinline__ unsigned short f2b(float f) {
  unsigned u = __float_as_uint(f);
  return (unsigned short)((u + 0x7fffu + ((u >> 16) & 1u)) >> 16);
}
__device__ __forceinline__ float b2f(unsigned short s) {
  return __uint_as_float(((unsigned)s) << 16);
}
__device__ __forceinline__ unsigned pkbf(float a, float b) {
  unsigned ua = (__float_as_uint(a) + 0x8000u) >> 16;
  unsigned ub = (__float_as_uint(b) + 0x8000u) & 0xffff0000u;
  return ua | ub;
}

// async global->LDS, 16B per lane; LDS dest must be lane-linear (base + lane*16).
__device__ __forceinline__ void gload_lds16(const void* g, void* l) {
#if __has_builtin(__builtin_amdgcn_global_load_lds)
  __builtin_amdgcn_global_load_lds(
      (const __attribute__((address_space(1))) unsigned int*)g,
      (__attribute__((address_space(3))) unsigned int*)l, 16, 0, 0);
#else
  *(uint4*)l = *(const uint4*)g;
#endif
}

#define SCB() __builtin_amdgcn_sched_barrier(0)

__device__ __forceinline__ void barx() {
  asm volatile("" ::: "memory");
  __builtin_amdgcn_s_barrier();
  asm volatile("" ::: "memory");
}

// ---------------- kernel 1: f32 -> bf16 convert (8 elems/thread) --------------
__global__ __launch_bounds__(256) void cvt_bf16_kernel(
    const float* __restrict__ src, ushort_t* __restrict__ dst, int n8)
{
  int i = blockIdx.x * 256 + threadIdx.x;
  if (i >= n8) return;
  const float4* s = (const float4*)src + (size_t)i * 2;
  float4 a = s[0], b = s[1];
  union { ushort_t u[8]; uint4 v; } o;
  o.u[0] = f2b(a.x); o.u[1] = f2b(a.y); o.u[2] = f2b(a.z); o.u[3] = f2b(a.w);
  o.u[4] = f2b(b.x); o.u[5] = f2b(b.y); o.u[6] = f2b(b.z); o.u[7] = f2b(b.w);
  ((uint4*)dst)[i] = o.v;
}

// ---------------- kernel 2: QKV GEMM, 256x256 tile, 8-phase pipeline ----------
// C[m][n] = A[m][:].Bw[n][:] + bias[n]; A=[4608][3072], Bw=[9216][3072] (B^T)
// 512 threads = 8 waves (2M x 4N), per-wave 128x64 output, BK=64, 2 K-tiles/iter.
// LDS 128KiB: buf{0,1} x { A0,A1,B0,B1 } half-tiles of 128x64 bf16 (16KiB each).
// Ledger (per wave, vmem group = 4 loads): at W1 (P4) in flight = prev-d,a,b ->
// vmcnt(4) completes prev-d+a => buf1 tile resident for P5. At W2 (P8) in
// flight = b,c,d -> vmcnt(4) completes b+c => buf0 tile resident for next P1.
// Restage margins all >=1 barrier after last read of old contents.
// RACE HARDENING: every sync point bracketed by sched_barrier(0) — hipcc moves
// ops across inline-asm waits/barriers despite "memory" clobbers (rule #18);
// verified fix (R1 race -> R2 pass).
#define NITER 24   // 3072 / (2*64)

// stage one 128x64 half-tile (2 x global_load_lds, 8KB each)
#define STG(Gp, rowbase, kt, ldsoff) do {                                          \
    gload_lds16((Gp) + (size_t)((rowbase) + sr) * DD + (kt) * 64 + sgk,            \
                smem + (ldsoff) + t * 16);                                         \
    gload_lds16((Gp) + (size_t)((rowbase) + 64 + sr) * DD + (kt) * 64 + sgk,       \
                smem + (ldsoff) + 8192 + t * 16);                                  \
  } while (0)

#define LOADA(base, mh) do {                                                       \
    _Pragma("unroll") for (int ii = 0; ii < 4; ++ii) {                             \
      int rl = (mh) * 64 + ii * 16 + lq;                                           \
      _Pragma("unroll") for (int ks = 0; ks < 2; ++ks) {                           \
        int ph = ((ks << 2) | quad) ^ (lq & 7);                                    \
        af[ii][ks] = *(const bf16x8*)(smem + (base) + rl * 128 + ph * 16);         \
      }                                                                            \
    } } while (0)

#define LOADB(base, nh) do {                                                       \
    _Pragma("unroll") for (int jj = 0; jj < 2; ++jj) {                             \
      int j = (nh) * 2 + jj;                                                       \
      int rl = (wni & 1) * 64 + j * 16 + lq;                                       \
      _Pragma("unroll") for (int ks = 0; ks < 2; ++ks) {                           \
        int ph = ((ks << 2) | quad) ^ (lq & 7);                                    \
        bfr[j][ks] = *(const bf16x8*)(smem + (base) + rl * 128 + ph * 16);         \
      }                                                                            \
    } } while (0)

#define MFMAQ(mh, nh) do {                                                         \
    _Pragma("unroll") for (int ii = 0; ii < 4; ++ii)                               \
      _Pragma("unroll") for (int jj = 0; jj < 2; ++jj)                             \
        _Pragma("unroll") for (int ks = 0; ks < 2; ++ks)                           \
          acc[(mh) * 4 + ii][(nh) * 2 + jj] =                                      \
              __builtin_amdgcn_mfma_f32_16x16x32_bf16(                             \
                  af[ii][ks], bfr[(nh) * 2 + jj][ks],                              \
                  acc[(mh) * 4 + ii][(nh) * 2 + jj], 0, 0, 0);                     \
  } while (0)

// S1 -> S2 boundary: barrier, wait own ds_reads, enter MFMA cluster
#define PH_MID() do {                                                              \
    SCB(); barx(); SCB();                                                          \
    asm volatile("s_waitcnt lgkmcnt(0)" ::: "memory");                             \
    SCB();                                                                         \
    __builtin_amdgcn_s_setprio(1);                                                 \
  } while (0)

// end of a non-publishing phase
#define PH_END() do {                                                              \
    __builtin_amdgcn_s_setprio(0);                                                 \
    SCB(); barx(); SCB();                                                          \
  } while (0)

// end of a publishing phase (counted vmem wait before barrier)
#define PH_END_W(NWAIT) do {                                                       \
    __builtin_amdgcn_s_setprio(0);                                                 \
    SCB();                                                                         \
    asm volatile("s_waitcnt vmcnt(" #NWAIT ")" ::: "memory");                      \
    SCB(); barx(); SCB();                                                          \
  } while (0)

#define ONE_ITER(NL, TA) do {                                                      \
    const int tb_ = (TA) + 1;                                                      \
    /* P1: tile a Q(0,0); stage buf1.A0 <- tb */                                   \
    LOADA(aoffA, 0); LOADB(boffA, 0);                                              \
    STG(A, m0, tb_, 65536);                                                        \
    PH_MID(); MFMAQ(0, 0); PH_END();                                               \
    /* P2: tile a Q(0,1); stage buf1.A1 <- tb */                                   \
    LOADB(boffA, 1);                                                               \
    STG(A, m0 + 128, tb_, 65536 + 16384);                                          \
    PH_MID(); MFMAQ(0, 1); PH_END();                                               \
    /* P3: tile a Q(1,1); stage buf0.B0 <- ta+2 */                                 \
    LOADA(aoffA, 1);                                                               \
    if (NL) STG(Bw, n0, (TA) + 2, 32768);                                          \
    PH_MID(); MFMAQ(1, 1); PH_END();                                               \
    /* P4: tile a Q(1,0); stage buf0.B1 <- ta+2; publish buf1 (tile b) */          \
    if (NL) STG(Bw, n0 + 128, (TA) + 2, 49152);                                    \
    PH_MID(); MFMAQ(1, 0);                                                         \
    if (NL) { PH_END_W(4); } else { PH_END_W(0); }                                 \
    /* P5: tile b Q(0,0); stage buf0.A0 <- ta+2 */                                 \
    LOADA(65536 + aoffA, 0); LOADB(65536 + boffA, 0);                              \
    if (NL) STG(A, m0, (TA) + 2, 0);                                               \
    PH_MID(); MFMAQ(0, 0); PH_END();                                               \
    /* P6: tile b Q(0,1); stage buf0.A1 <- ta+2 */                                 \
    LOADB(65536 + boffA, 1);                                                       \
    if (NL) STG(A, m0 + 128, (TA) + 2, 16384);                                     \
    PH_MID(); MFMAQ(0, 1); PH_END();                                               \
    /* P7: tile b Q(1,1); stage buf1.B0 <- tb+2 */                                 \
    LOADA(65536 + aoffA, 1);                                                       \
    if (NL) STG(Bw, n0, tb_ + 2, 98304);                                           \
    PH_MID(); MFMAQ(1, 1); PH_END();                                               \
    /* P8: tile b Q(1,0); stage buf1.B1 <- tb+2; publish buf0 (tile a+2) */        \
    if (NL) STG(Bw, n0 + 128, tb_ + 2, 114688);                                    \
    PH_MID(); MFMAQ(1, 0);                                                         \
    if (NL) { PH_END_W(4); } else { PH_END(); }                                    \
  } while (0)

__global__ __launch_bounds__(512, 2) void gemm_qkv_kernel(
    const ushort_t* __restrict__ A, const ushort_t* __restrict__ Bw,
    const float* __restrict__ bias, ushort_t* __restrict__ C)
{
  __shared__ char smem[131072];
  const int t = threadIdx.x;
  const int w = t >> 6, l = t & 63;
  const int quad = l >> 4, lq = l & 15;
  const int wmi = w >> 2, wni = w & 3;

  // bijective XCD swizzle: 648 blocks = 8 * 81
  int orig = blockIdx.y * 36 + blockIdx.x;
  int swz = (orig & 7) * 81 + (orig >> 3);
  const int m0 = (swz / 36) * 256;
  const int n0 = (swz % 36) * 256;

  const int aoffA = wmi * 16384;               // this wave's A half-tile (buf0)
  const int boffA = 32768 + (wni >> 1) * 16384;// this wave's B half-tile (buf0)
  const int sr = t >> 3, ssub = t & 7;         // staging row/sub (call0; call1 = +64 rows)
  const int sgk = (ssub ^ (sr & 7)) << 3;      // swizzled source chunk offset (elems)

  f32x4 acc[8][4] = {};
  bf16x8 af[4][2], bfr[4][2];

  // prologue: tile0 (all 4 halves, buf0) + tile1 B halves (buf1), then wait tile0
  STG(A,  m0,       0, 0);
  STG(A,  m0 + 128, 0, 16384);
  STG(Bw, n0,       0, 32768);
  STG(Bw, n0 + 128, 0, 49152);
  STG(Bw, n0,       1, 98304);
  STG(Bw, n0 + 128, 1, 114688);
  SCB();
  asm volatile("s_waitcnt vmcnt(4)" ::: "memory");
  SCB(); barx(); SCB();

  for (int it = 0; it < NITER - 1; ++it) {
    ONE_ITER(1, 2 * it);
  }
  ONE_ITER(0, 2 * (NITER - 1));

  // epilogue: bias + bf16 store
#pragma unroll
  for (int j = 0; j < 4; ++j) {
    int n = n0 + wni * 64 + j * 16 + lq;
    float bj = bias[n];
#pragma unroll
    for (int i = 0; i < 8; ++i) {
      int mb = m0 + wmi * 128 + i * 16 + quad * 4;
#pragma unroll
      for (int r = 0; r < 4; ++r)
        C[(size_t)(mb + r) * NN3 + n] = f2b(acc[i][j][r] + bj);
    }
  }
}

// ---------------- kernel 3: RMSNorm + interleaved RoPE, in-place on q,k -------
__global__ __launch_bounds__(256) void norm_rope_kernel(
    ushort_t* __restrict__ qkv, const float* __restrict__ wq,
    const float* __restrict__ wk, const float* __restrict__ cosb,
    const float* __restrict__ sinb, const int* __restrict__ tptr)
{
  const int T = *tptr;
  const int t = threadIdx.x, w = t >> 6, l = t & 63;
  int task = blockIdx.x * 4 + w;
  int which = task & 1;
  int rest = task >> 1;
  int h = rest % HEADS;
  int sm = rest / HEADS;
  int s = sm % SS;
  size_t base = (size_t)sm * NN3 + which * DD + h * HD + 2 * l;
  unsigned pr = *(const unsigned*)(qkv + base);
  float x1 = b2f((unsigned short)(pr & 0xffffu));
  float x2 = b2f((unsigned short)(pr >> 16));
  float ss = x1 * x1 + x2 * x2;
#pragma unroll
  for (int m = 1; m < 64; m <<= 1) ss += __shfl_xor(ss, m, 64);
  float rr = rsqrtf(ss * (1.0f / 128.0f) + 1e-6f);
  const float* wn = which ? wk : wq;
  float y1 = x1 * rr * wn[2 * l], y2 = x2 * rr * wn[2 * l + 1];
  if (s >= T) {
    float c = cosb[(size_t)(s - T) * 64 + l];
    float sn = sinb[(size_t)(s - T) * 64 + l];
    float o1 = y1 * c - y2 * sn;
    float o2 = y2 * c + y1 * sn;
    y1 = o1; y2 = o2;
  }
  *(unsigned*)(qkv + base) = (unsigned)f2b(y1) | ((unsigned)f2b(y2) << 16);
}

// ---------------- kernel 4: V transpose -> vt[b][h][d][S] ---------------------
__global__ __launch_bounds__(256) void vtrans_kernel(
    const ushort_t* __restrict__ qkv, ushort_t* __restrict__ vt)
{
  __shared__ ushort_t Tl[HD * 73];
  const int t = threadIdx.x;
  const int st = blockIdx.x;
  const int bh = blockIdx.y;
  const int b = bh / HEADS, h = bh % HEADS;
  const int s0 = st * 64;
  const ushort_t* vsrc = qkv + (size_t)(b * SS) * NN3 + 2 * DD + h * HD;
#pragma unroll
  for (int i = 0; i < 4; ++i) {
    int c = i * 256 + t;
    int s = c >> 4, dc = c & 15;
    uint4 v4 = *(const uint4*)(vsrc + (size_t)(s0 + s) * NN3 + dc * 8);
    union { uint4 v; ushort_t u[8]; } un; un.v = v4;
#pragma unroll
    for (int j = 0; j < 8; ++j) Tl[(dc * 8 + j) * 73 + s] = un.u[j];
  }
  __syncthreads();
  ushort_t* vdst = vt + (size_t)bh * HD * SS;
#pragma unroll
  for (int i = 0; i < 4; ++i) {
    int c = i * 256 + t;
    int d = c >> 3, sc = c & 7;
    union { uint4 v; ushort_t u[8]; } un;
#pragma unroll
    for (int j = 0; j < 8; ++j) un.u[j] = Tl[d * 73 + sc * 8 + j];
    *(uint4*)(vdst + (size_t)d * SS + s0 + sc * 8) = un.v;
  }
}

// ---------------- kernel 5: flash attention, NO online softmax ---------------
// |q|=|k|=sqrt(128) after RMSNorm(w=1) => |q.k| <= 128 (hard bound), so
// P = exp2(S*log2e/sqrt(128) - 8) needs no running max (max arg 8.32).
// Row-sum l accumulated on the MFMA pipe via an all-ones A-fragment.
// R3: each block processes TWO q-tiles sequentially (q-range 256): pass 2's
// KV walk hits L2/LLC (1.18 MB resident) -> HBM KV traffic halves. Grid 432
// blocks @ 2/CU = full residency, zero tail. Bijective XCD remap (432 = 8*54)
// co-locates the 9 q-blocks sharing one (b,h) on one XCD's L2.
__global__ __launch_bounds__(256, 2) void attn_kernel(
    const ushort_t* __restrict__ qkv, const ushort_t* __restrict__ vt,
    float* __restrict__ out)
{
  __shared__ char smem[65536];   // K0|K1|V0|V1 (16K each); epilogue reuses all 64K
  const int t = threadIdx.x;
  const int w = t >> 6, l = t & 63, quad = l >> 4, lq = l & 15;

  // XCD remap: linear id -> (qt, bh) with same-bh blocks on one XCD
  int lid = blockIdx.y * 9 + blockIdx.x;     // dispatch-linear (x fastest)
  int xcd = lid & 7, g = lid >> 3;           // g in [0,54)
  int qt = g % 9;
  int bh = ((g / 9) << 3) | xcd;             // bh in [0,48)
  const int b = bh / HEADS, h = bh % HEADS;
  const ushort_t* qb = qkv + (size_t)(b * SS) * NN3 + h * HD;
  const ushort_t* Kg = qb + DD;
  const ushort_t* Vg = vt + (size_t)bh * HD * SS;

  frag_u ones;
  ones.d[0] = 0x3f803f80u; ones.d[1] = 0x3f803f80u;
  ones.d[2] = 0x3f803f80u; ones.d[3] = 0x3f803f80u;

  const float SC2 = 0.1275174315402f;    // (1/sqrt(128)) * log2(e)
  const int rb = ((lq >> 2) << 3) | (lq & 3);

  for (int qpass = 0; qpass < 2; ++qpass) {
    const int q0 = qt * 256 + qpass * 128;

    // Q B-fragments (col n = q = lq, k = d = kc*32 + quad*8 + [0,8))
    frag_u aq[2][4];
#pragma unroll
    for (int m = 0; m < 2; ++m) {
      size_t ro = (size_t)(q0 + w * 32 + m * 16 + lq) * NN3;
#pragma unroll
      for (int kc = 0; kc < 4; ++kc)
        aq[m][kc].v = *(const uint4*)(qb + ro + kc * 32 + quad * 8);
    }

    f32x4 o[2][8] = {};
    f32x4 lacc[2] = {};

    // prologue: issue tile 0 into buffer 0 (prev epilogue's __syncthreads
    // ordered all reads of smem before these writes)
    {
#pragma unroll
      for (int i = 0; i < 4; ++i) {
        int n = i * 256 + t;
        int kv = n >> 4, c = n & 15;
        gload_lds16(Kg + (size_t)kv * NN3 + ((c ^ (kv & 15)) << 3), smem + n * 16);
      }
#pragma unroll
      for (int i = 0; i < 4; ++i) {
        int n = i * 256 + t;
        int dr = n >> 3, c = n & 7;
        gload_lds16(Vg + (size_t)dr * SS + ((c ^ (dr & 7)) << 3), smem + 32768 + n * 16);
      }
    }

    for (int kt = 0; kt < 36; ++kt) {
      char* Ksh = smem + (kt & 1) * 16384;
      char* Vsh = smem + 32768 + (kt & 1) * 16384;
      __syncthreads();                     // publish tile kt (drains vmcnt)
      if (kt + 1 < 36) {
        const int kv1 = (kt + 1) * 64;
        char* Kn = smem + ((kt + 1) & 1) * 16384;
        char* Vn = smem + 32768 + ((kt + 1) & 1) * 16384;
#pragma unroll
        for (int i = 0; i < 4; ++i) {
          int n = i * 256 + t;
          int kv = n >> 4, c = n & 15;
          gload_lds16(Kg + (size_t)(kv1 + kv) * NN3 + ((c ^ (kv & 15)) << 3), Kn + n * 16);
        }
#pragma unroll
        for (int i = 0; i < 4; ++i) {
          int n = i * 256 + t;
          int dr = n >> 3, c = n & 7;
          gload_lds16(Vg + (size_t)dr * SS + kv1 + ((c ^ (dr & 7)) << 3), Vn + n * 16);
        }
      }

      // S^T tiles: sv[m][kvb][r] = S^T[kappa][q=lq]
      f32x4 sv[2][4] = {};
#pragma unroll
      for (int kc = 0; kc < 4; ++kc) {
#pragma unroll
        for (int kvb = 0; kvb < 4; ++kvb) {
          int row = ((kvb & 2) << 4) + ((kvb & 1) << 2) + rb;
          int swz = ((kc << 2) | quad) ^ (row & 15);
          frag_u a; a.v = *(const uint4*)(Ksh + row * 256 + swz * 16);
          sv[0][kvb] = __builtin_amdgcn_mfma_f32_16x16x32_bf16(a.f, aq[0][kc].f, sv[0][kvb], 0, 0, 0);
          sv[1][kvb] = __builtin_amdgcn_mfma_f32_16x16x32_bf16(a.f, aq[1][kc].f, sv[1][kvb], 0, 0, 0);
        }
      }

      // P = exp2(S*SC2 - 8), packed straight into PV B-frag dwords.
      uint2 pb[2][4];
#pragma unroll
      for (int m = 0; m < 2; ++m) {
#pragma unroll
        for (int kvb = 0; kvb < 4; ++kvb) {
          float p0 = exp2f(fmaf(sv[m][kvb][0], SC2, -8.0f));
          float p1 = exp2f(fmaf(sv[m][kvb][1], SC2, -8.0f));
          float p2 = exp2f(fmaf(sv[m][kvb][2], SC2, -8.0f));
          float p3 = exp2f(fmaf(sv[m][kvb][3], SC2, -8.0f));
          pb[m][kvb].x = pkbf(p0, p1);
          pb[m][kvb].y = pkbf(p2, p3);
        }
      }

      // O^T += V^T P^T ; l += ones . P (same MFMA pipe, same q=lq layout)
#pragma unroll
      for (int kc2 = 0; kc2 < 2; ++kc2) {
        frag_u pf0, pf1;
        pf0.d[0] = pb[0][kc2 * 2].x;     pf0.d[1] = pb[0][kc2 * 2].y;
        pf0.d[2] = pb[0][kc2 * 2 + 1].x; pf0.d[3] = pb[0][kc2 * 2 + 1].y;
        pf1.d[0] = pb[1][kc2 * 2].x;     pf1.d[1] = pb[1][kc2 * 2].y;
        pf1.d[2] = pb[1][kc2 * 2 + 1].x; pf1.d[3] = pb[1][kc2 * 2 + 1].y;
        lacc[0] = __builtin_amdgcn_mfma_f32_16x16x32_bf16(ones.f, pf0.f, lacc[0], 0, 0, 0);
        lacc[1] = __builtin_amdgcn_mfma_f32_16x16x32_bf16(ones.f, pf1.f, lacc[1], 0, 0, 0);
#pragma unroll
        for (int dt = 0; dt < 8; ++dt) {
          int row = dt * 16 + lq;
          int swz = ((kc2 << 2) | quad) ^ (row & 7);
          frag_u a; a.v = *(const uint4*)(Vsh + row * 128 + swz * 16);
          o[0][dt] = __builtin_amdgcn_mfma_f32_16x16x32_bf16(a.f, pf0.f, o[0][dt], 0, 0, 0);
          o[1][dt] = __builtin_amdgcn_mfma_f32_16x16x32_bf16(a.f, pf1.f, o[1][dt], 0, 0, 0);
        }
      }
    }

    // epilogue: O^T -> LDS transpose (swizzled) -> coalesced f32x4 global stores
    __syncthreads();
#pragma unroll
    for (int mch = 0; mch < 2; ++mch) {
      float inv = 1.0f / lacc[mch][0];   // l for q-column lq (all 4 regs identical)
      int row = w * 16 + lq;
#pragma unroll
      for (int dt = 0; dt < 8; ++dt) {
        f32x4 val = o[mch][dt] * inv;
        int swz = ((dt << 2) | quad) ^ (row & 31);
        *(f32x4*)(smem + row * 512 + swz * 16) = val;
      }
      __syncthreads();
#pragma unroll
      for (int i = 0; i < 8; ++i) {
        int n = i * 256 + t;
        int rr = n >> 5, c = n & 31;
        f32x4 v = *(const f32x4*)(smem + rr * 512 + ((c ^ (rr & 31)) << 4));
        int qg = q0 + ((rr >> 4) << 5) + (mch << 4) + (rr & 15);
        *(f32x4*)(out + (size_t)(b * SS + qg) * DD + h * HD + c * 4) = v;
      }
      __syncthreads();
    }
  }
}

// ---------------- launch ------------------------------------------------------
extern "C" void kernel_launch(void* const* d_in, const int* in_sizes, int n_in,
                              void* d_out, int out_size, void* d_ws, size_t ws_size,
                              hipStream_t stream)
{
  const float* hs   = (const float*)d_in[0];
  const float* wqkv = (const float*)d_in[1];
  const float* bq   = (const float*)d_in[2];
  const float* wqn  = (const float*)d_in[3];
  const float* wkn  = (const float*)d_in[4];
  const float* cosb = (const float*)d_in[5];
  const float* sinb = (const float*)d_in[6];
  const int*   tseq = (const int*)d_in[7];
  float* out = (float*)d_out;
  char* ws = (char*)d_ws;

  ushort_t* hsb  = (ushort_t*)ws;                               // 28,311,552 B
  ushort_t* wb   = (ushort_t*)(ws + 28311552);                  // 56,623,104 B
  ushort_t* qkvb = (ushort_t*)(ws + 28311552 + 56623104);       // 84,934,656 B
  ushort_t* vtb  = hsb;                                         // alias (spent after GEMM)

  cvt_bf16_kernel<<<6912, 256, 0, stream>>>(hs, hsb, 1769472);
  cvt_bf16_kernel<<<13824, 256, 0, stream>>>(wqkv, wb, 3538944);
  gemm_qkv_kernel<<<dim3(36, 18), 512, 0, stream>>>(hsb, wb, bq, qkvb);
  norm_rope_kernel<<<55296, 256, 0, stream>>>(qkvb, wqn, wkn, cosb, sinb, tseq);
  vtrans_kernel<<<dim3(36, 48), 256, 0, stream>>>(qkvb, vtb);
  attn_kernel<<<dim3(9, 48), 256, 0, stream>>>(qkvb, vtb, out);
}

// Round 5
// 709.130 us; speedup vs baseline: 1.0304x; 1.0304x over previous
//
#include <hip/hip_runtime.h>
#include <stdint.h>
#include <stddef.h>

#define HEADS 24
#define HD    128
#define BB    2
#define SS    2304
#define DD    3072      // HEADS*HD
#define NN3   9216      // 3*DD
#define MM    4608      // BB*SS

typedef unsigned short ushort_t;
typedef __bf16 bf16x8 __attribute__((ext_vector_type(8)));
typedef float  f32x4  __attribute__((ext_vector_type(4)));

union frag_u { bf16x8 f; uint4 v; unsigned d[4]; };

__device__ __forceinline__ unsigned short f2b(float f) {
  unsigned u = __float_as_uint(f);
  return (unsigned short)((u + 0x7fffu + ((u >> 16) & 1u)) >> 16);
}
__device__ __forceinline__ float b2f(unsigned short s) {
  return __uint_as_float(((unsigned)s) << 16);
}
__device__ __forceinline__ unsigned pkbf(float a, float b) {
  unsigned ua = (__float_as_uint(a) + 0x8000u) >> 16;
  unsigned ub = (__float_as_uint(b) + 0x8000u) & 0xffff0000u;
  return ua | ub;
}

// async global->LDS, 16B per lane; LDS dest must be lane-linear (base + lane*16).
__device__ __forceinline__ void gload_lds16(const void* g, void* l) {
#if __has_builtin(__builtin_amdgcn_global_load_lds)
  __builtin_amdgcn_global_load_lds(
      (const __attribute__((address_space(1))) unsigned int*)g,
      (__attribute__((address_space(3))) unsigned int*)l, 16, 0, 0);
#else
  *(uint4*)l = *(const uint4*)g;
#endif
}

#define SCB() __builtin_amdgcn_sched_barrier(0)

__device__ __forceinline__ void barx() {
  asm volatile("" ::: "memory");
  __builtin_amdgcn_s_barrier();
  asm volatile("" ::: "memory");
}

// ---------------- kernel 1: f32 -> bf16 convert (8 elems/thread) --------------
__global__ __launch_bounds__(256) void cvt_bf16_kernel(
    const float* __restrict__ src, ushort_t* __restrict__ dst, int n8)
{
  int i = blockIdx.x * 256 + threadIdx.x;
  if (i >= n8) return;
  const float4* s = (const float4*)src + (size_t)i * 2;
  float4 a = s[0], b = s[1];
  union { ushort_t u[8]; uint4 v; } o;
  o.u[0] = f2b(a.x); o.u[1] = f2b(a.y); o.u[2] = f2b(a.z); o.u[3] = f2b(a.w);
  o.u[4] = f2b(b.x); o.u[5] = f2b(b.y); o.u[6] = f2b(b.z); o.u[7] = f2b(b.w);
  ((uint4*)dst)[i] = o.v;
}

// ---------------- kernel 2: QKV GEMM, 256x256 tile, 8-phase pipeline ----------
// C[m][n] = A[m][:].Bw[n][:] + bias[n]; A=[4608][3072], Bw=[9216][3072] (B^T)
// 512 threads = 8 waves (2M x 4N), per-wave 128x64 output, BK=64, 2 K-tiles/iter.
// LDS 128KiB: buf{0,1} x { A0,A1,B0,B1 } half-tiles of 128x64 bf16 (16KiB each).
// Ledger (per wave, vmem group = 4 loads): at W1 (P4) in flight = prev-d,a,b ->
// vmcnt(4) completes prev-d+a => buf1 tile resident for P5. At W2 (P8) in
// flight = b,c,d -> vmcnt(4) completes b+c => buf0 tile resident for next P1.
// Restage margins all >=1 barrier after last read of old contents.
// RACE HARDENING: every sync point bracketed by sched_barrier(0) — hipcc moves
// ops across inline-asm waits/barriers despite "memory" clobbers (rule #18);
// verified fix (R1 race -> R2 pass).
// R4: epilogue stages C-tile in LDS (bf16, exactly 128KiB) -> coalesced
// dwordx4 stores; kills the 1.84x partial-line write amplification
// (WRITE_SIZE 156MB -> ~88MB) of the old per-element bf16 stores.
#define NITER 24   // 3072 / (2*64)

// stage one 128x64 half-tile (2 x global_load_lds, 8KB each)
#define STG(Gp, rowbase, kt, ldsoff) do {                                          \
    gload_lds16((Gp) + (size_t)((rowbase) + sr) * DD + (kt) * 64 + sgk,            \
                smem + (ldsoff) + t * 16);                                         \
    gload_lds16((Gp) + (size_t)((rowbase) + 64 + sr) * DD + (kt) * 64 + sgk,       \
                smem + (ldsoff) + 8192 + t * 16);                                  \
  } while (0)

#define LOADA(base, mh) do {                                                       \
    _Pragma("unroll") for (int ii = 0; ii < 4; ++ii) {                             \
      int rl = (mh) * 64 + ii * 16 + lq;                                           \
      _Pragma("unroll") for (int ks = 0; ks < 2; ++ks) {                           \
        int ph = ((ks << 2) | quad) ^ (lq & 7);                                    \
        af[ii][ks] = *(const bf16x8*)(smem + (base) + rl * 128 + ph * 16);         \
      }                                                                            \
    } } while (0)

#define LOADB(base, nh) do {                                                       \
    _Pragma("unroll") for (int jj = 0; jj < 2; ++jj) {                             \
      int j = (nh) * 2 + jj;                                                       \
      int rl = (wni & 1) * 64 + j * 16 + lq;                                       \
      _Pragma("unroll") for (int ks = 0; ks < 2; ++ks) {                           \
        int ph = ((ks << 2) | quad) ^ (lq & 7);                                    \
        bfr[j][ks] = *(const bf16x8*)(smem + (base) + rl * 128 + ph * 16);         \
      }                                                                            \
    } } while (0)

#define MFMAQ(mh, nh) do {                                                         \
    _Pragma("unroll") for (int ii = 0; ii < 4; ++ii)                               \
      _Pragma("unroll") for (int jj = 0; jj < 2; ++jj)                             \
        _Pragma("unroll") for (int ks = 0; ks < 2; ++ks)                           \
          acc[(mh) * 4 + ii][(nh) * 2 + jj] =                                      \
              __builtin_amdgcn_mfma_f32_16x16x32_bf16(                             \
                  af[ii][ks], bfr[(nh) * 2 + jj][ks],                              \
                  acc[(mh) * 4 + ii][(nh) * 2 + jj], 0, 0, 0);                     \
  } while (0)

// S1 -> S2 boundary: barrier, wait own ds_reads, enter MFMA cluster
#define PH_MID() do {                                                              \
    SCB(); barx(); SCB();                                                          \
    asm volatile("s_waitcnt lgkmcnt(0)" ::: "memory");                             \
    SCB();                                                                         \
    __builtin_amdgcn_s_setprio(1);                                                 \
  } while (0)

// end of a non-publishing phase
#define PH_END() do {                                                              \
    __builtin_amdgcn_s_setprio(0);                                                 \
    SCB(); barx(); SCB();                                                          \
  } while (0)

// end of a publishing phase (counted vmem wait before barrier)
#define PH_END_W(NWAIT) do {                                                       \
    __builtin_amdgcn_s_setprio(0);                                                 \
    SCB();                                                                         \
    asm volatile("s_waitcnt vmcnt(" #NWAIT ")" ::: "memory");                      \
    SCB(); barx(); SCB();                                                          \
  } while (0)

#define ONE_ITER(NL, TA) do {                                                      \
    const int tb_ = (TA) + 1;                                                      \
    /* P1: tile a Q(0,0); stage buf1.A0 <- tb */                                   \
    LOADA(aoffA, 0); LOADB(boffA, 0);                                              \
    STG(A, m0, tb_, 65536);                                                        \
    PH_MID(); MFMAQ(0, 0); PH_END();                                               \
    /* P2: tile a Q(0,1); stage buf1.A1 <- tb */                                   \
    LOADB(boffA, 1);                                                               \
    STG(A, m0 + 128, tb_, 65536 + 16384);                                          \
    PH_MID(); MFMAQ(0, 1); PH_END();                                               \
    /* P3: tile a Q(1,1); stage buf0.B0 <- ta+2 */                                 \
    LOADA(aoffA, 1);                                                               \
    if (NL) STG(Bw, n0, (TA) + 2, 32768);                                          \
    PH_MID(); MFMAQ(1, 1); PH_END();                                               \
    /* P4: tile a Q(1,0); stage buf0.B1 <- ta+2; publish buf1 (tile b) */          \
    if (NL) STG(Bw, n0 + 128, (TA) + 2, 49152);                                    \
    PH_MID(); MFMAQ(1, 0);                                                         \
    if (NL) { PH_END_W(4); } else { PH_END_W(0); }                                 \
    /* P5: tile b Q(0,0); stage buf0.A0 <- ta+2 */                                 \
    LOADA(65536 + aoffA, 0); LOADB(65536 + boffA, 0);                              \
    if (NL) STG(A, m0, (TA) + 2, 0);                                               \
    PH_MID(); MFMAQ(0, 0); PH_END();                                               \
    /* P6: tile b Q(0,1); stage buf0.A1 <- ta+2 */                                 \
    LOADB(65536 + boffA, 1);                                                       \
    if (NL) STG(A, m0 + 128, (TA) + 2, 16384);                                     \
    PH_MID(); MFMAQ(0, 1); PH_END();                                               \
    /* P7: tile b Q(1,1); stage buf1.B0 <- tb+2 */                                 \
    LOADA(65536 + aoffA, 1);                                                       \
    if (NL) STG(Bw, n0, tb_ + 2, 98304);                                           \
    PH_MID(); MFMAQ(1, 1); PH_END();                                               \
    /* P8: tile b Q(1,0); stage buf1.B1 <- tb+2; publish buf0 (tile a+2) */        \
    if (NL) STG(Bw, n0 + 128, tb_ + 2, 114688);                                    \
    PH_MID(); MFMAQ(1, 0);                                                         \
    if (NL) { PH_END_W(4); } else { PH_END(); }                                    \
  } while (0)

__global__ __launch_bounds__(512, 2) void gemm_qkv_kernel(
    const ushort_t* __restrict__ A, const ushort_t* __restrict__ Bw,
    const float* __restrict__ bias, ushort_t* __restrict__ C)
{
  __shared__ char smem[131072];
  const int t = threadIdx.x;
  const int w = t >> 6, l = t & 63;
  const int quad = l >> 4, lq = l & 15;
  const int wmi = w >> 2, wni = w & 3;

  // bijective XCD swizzle: 648 blocks = 8 * 81
  int orig = blockIdx.y * 36 + blockIdx.x;
  int swz = (orig & 7) * 81 + (orig >> 3);
  const int m0 = (swz / 36) * 256;
  const int n0 = (swz % 36) * 256;

  const int aoffA = wmi * 16384;               // this wave's A half-tile (buf0)
  const int boffA = 32768 + (wni >> 1) * 16384;// this wave's B half-tile (buf0)
  const int sr = t >> 3, ssub = t & 7;         // staging row/sub (call0; call1 = +64 rows)
  const int sgk = (ssub ^ (sr & 7)) << 3;      // swizzled source chunk offset (elems)

  f32x4 acc[8][4] = {};
  bf16x8 af[4][2], bfr[4][2];

  // prologue: tile0 (all 4 halves, buf0) + tile1 B halves (buf1), then wait tile0
  STG(A,  m0,       0, 0);
  STG(A,  m0 + 128, 0, 16384);
  STG(Bw, n0,       0, 32768);
  STG(Bw, n0 + 128, 0, 49152);
  STG(Bw, n0,       1, 98304);
  STG(Bw, n0 + 128, 1, 114688);
  SCB();
  asm volatile("s_waitcnt vmcnt(4)" ::: "memory");
  SCB(); barx(); SCB();

  for (int it = 0; it < NITER - 1; ++it) {
    ONE_ITER(1, 2 * it);
  }
  ONE_ITER(0, 2 * (NITER - 1));

  // ---- epilogue: bias + bf16 C-tile in LDS (exactly 128KiB) -> coalesced stores
  // Main loop's final barx + per-wave lgkmcnt(0)-before-MFMA guarantees no wave
  // still has LDS reads in flight; each wave writes only its own 128x64 region.
#pragma unroll
  for (int j = 0; j < 4; ++j) {
    int n = wni * 64 + j * 16 + lq;
    float bj = bias[n0 + n];
#pragma unroll
    for (int i = 0; i < 8; ++i) {
      int mb = wmi * 128 + i * 16 + quad * 4;
#pragma unroll
      for (int r = 0; r < 4; ++r)
        *(ushort_t*)(smem + (size_t)(mb + r) * 512 + n * 2) = f2b(acc[i][j][r] + bj);
    }
  }
  SCB();
  asm volatile("s_waitcnt lgkmcnt(0)" ::: "memory");   // ds_writes visible
  SCB(); barx(); SCB();
#pragma unroll
  for (int c = 0; c < 16; ++c) {
    int idx = c * 512 + t;                // 8192 x 16B chunks of the 256x256 tile
    int row = idx >> 5, col = idx & 31;
    uint4 v = *(const uint4*)(smem + row * 512 + col * 16);
    *(uint4*)(C + (size_t)(m0 + row) * NN3 + n0 + col * 8) = v;
  }
}

// ---------------- kernel 3: RMSNorm + interleaved RoPE, in-place on q,k -------
// R4: 8B/lane vectorized; half-wave (32 lanes) owns one 128-elem row (2 pairs
// per lane), wave handles 2 tasks. Shuffle masks 1..16 stay within each half.
__global__ __launch_bounds__(256) void norm_rope_kernel(
    ushort_t* __restrict__ qkv, const float* __restrict__ wq,
    const float* __restrict__ wk, const float* __restrict__ cosb,
    const float* __restrict__ sinb, const int* __restrict__ tptr)
{
  const int T = *tptr;
  const int t = threadIdx.x, w = t >> 6, l = t & 63;
  const int lh = l & 31, half = l >> 5;
  int task = blockIdx.x * 8 + w * 2 + half;
  int which = task & 1;
  int rest = task >> 1;
  int h = rest % HEADS;
  int sm = rest / HEADS;
  int s = sm % SS;
  size_t base = (size_t)sm * NN3 + which * DD + h * HD + 4 * lh;
  uint2 pr = *(const uint2*)(qkv + base);
  float x1 = b2f((unsigned short)(pr.x & 0xffffu));
  float x2 = b2f((unsigned short)(pr.x >> 16));
  float x3 = b2f((unsigned short)(pr.y & 0xffffu));
  float x4 = b2f((unsigned short)(pr.y >> 16));
  float ss = x1 * x1 + x2 * x2 + x3 * x3 + x4 * x4;
#pragma unroll
  for (int m = 1; m < 32; m <<= 1) ss += __shfl_xor(ss, m, 64);
  float rr = rsqrtf(ss * (1.0f / 128.0f) + 1e-6f);
  const float* wn = which ? wk : wq;
  float4 wv = *(const float4*)(wn + 4 * lh);
  float y1 = x1 * rr * wv.x, y2 = x2 * rr * wv.y;
  float y3 = x3 * rr * wv.z, y4 = x4 * rr * wv.w;
  if (s >= T) {
    float2 cv = *(const float2*)(cosb + (size_t)(s - T) * 64 + 2 * lh);
    float2 sv = *(const float2*)(sinb + (size_t)(s - T) * 64 + 2 * lh);
    float o1 = y1 * cv.x - y2 * sv.x, o2 = y2 * cv.x + y1 * sv.x;
    float o3 = y3 * cv.y - y4 * sv.y, o4 = y4 * cv.y + y3 * sv.y;
    y1 = o1; y2 = o2; y3 = o3; y4 = o4;
  }
  uint2 ow;
  ow.x = (unsigned)f2b(y1) | ((unsigned)f2b(y2) << 16);
  ow.y = (unsigned)f2b(y3) | ((unsigned)f2b(y4) << 16);
  *(uint2*)(qkv + base) = ow;
}

// ---------------- kernel 4: V transpose -> vt[b][h][d][S] ---------------------
__global__ __launch_bounds__(256) void vtrans_kernel(
    const ushort_t* __restrict__ qkv, ushort_t* __restrict__ vt)
{
  __shared__ ushort_t Tl[HD * 73];
  const int t = threadIdx.x;
  const int st = blockIdx.x;
  const int bh = blockIdx.y;
  const int b = bh / HEADS, h = bh % HEADS;
  const int s0 = st * 64;
  const ushort_t* vsrc = qkv + (size_t)(b * SS) * NN3 + 2 * DD + h * HD;
#pragma unroll
  for (int i = 0; i < 4; ++i) {
    int c = i * 256 + t;
    int s = c >> 4, dc = c & 15;
    uint4 v4 = *(const uint4*)(vsrc + (size_t)(s0 + s) * NN3 + dc * 8);
    union { uint4 v; ushort_t u[8]; } un; un.v = v4;
#pragma unroll
    for (int j = 0; j < 8; ++j) Tl[(dc * 8 + j) * 73 + s] = un.u[j];
  }
  __syncthreads();
  ushort_t* vdst = vt + (size_t)bh * HD * SS;
#pragma unroll
  for (int i = 0; i < 4; ++i) {
    int c = i * 256 + t;
    int d = c >> 3, sc = c & 7;
    union { uint4 v; ushort_t u[8]; } un;
#pragma unroll
    for (int j = 0; j < 8; ++j) un.u[j] = Tl[d * 73 + sc * 8 + j];
    *(uint4*)(vdst + (size_t)d * SS + s0 + sc * 8) = un.v;
  }
}

// ---------------- kernel 5: flash attention, NO online softmax ---------------
// |q|=|k|=sqrt(128) after RMSNorm(w=1) => |q.k| <= 128 (hard bound), so
// P = exp2(S*log2e/sqrt(128) - 8) needs no running max: max arg 8.32
// (P<=320, l<=7.4e5 in f32), min P ~2^-24 (bf16-normal). O/l identical to
// softmax. Row-sum l accumulated FREE on the MFMA pipe via an all-ones
// A-fragment (D[i][q]=sum_kv P[kv][q], same q=lq column layout as O accum).
// No shuffles, no rescale, no serial chain in the loop.
// (R2 version restored: R3's 2-pass KV-reuse variant was neutral-to-negative —
// attn is not HBM-BW-bound.)
__global__ __launch_bounds__(256, 2) void attn_kernel(
    const ushort_t* __restrict__ qkv, const ushort_t* __restrict__ vt,
    float* __restrict__ out)
{
  __shared__ char smem[65536];   // K0|K1|V0|V1 (16K each); epilogue reuses [0,32K)
  const int t = threadIdx.x;
  const int w = t >> 6, l = t & 63, quad = l >> 4, lq = l & 15;
  const int qt = blockIdx.x, bh = blockIdx.y;
  const int b = bh / HEADS, h = bh % HEADS;
  const int q0 = qt * 128;
  const ushort_t* qb = qkv + (size_t)(b * SS) * NN3 + h * HD;
  const ushort_t* Kg = qb + DD;
  const ushort_t* Vg = vt + (size_t)bh * HD * SS;

  // Q B-fragments (col n = q = lq, k = d = kc*32 + quad*8 + [0,8))
  frag_u aq[2][4];
#pragma unroll
  for (int m = 0; m < 2; ++m) {
    size_t ro = (size_t)(q0 + w * 32 + m * 16 + lq) * NN3;
#pragma unroll
    for (int kc = 0; kc < 4; ++kc)
      aq[m][kc].v = *(const uint4*)(qb + ro + kc * 32 + quad * 8);
  }

  frag_u ones;
  ones.d[0] = 0x3f803f80u; ones.d[1] = 0x3f803f80u;
  ones.d[2] = 0x3f803f80u; ones.d[3] = 0x3f803f80u;

  f32x4 o[2][8] = {};
  f32x4 lacc[2] = {};
  const float SC2 = 0.1275174315402f;    // (1/sqrt(128)) * log2(e)
  const int rb = ((lq >> 2) << 3) | (lq & 3);

  // prologue: issue tile 0 into buffer 0
  {
#pragma unroll
    for (int i = 0; i < 4; ++i) {
      int n = i * 256 + t;
      int kv = n >> 4, c = n & 15;
      gload_lds16(Kg + (size_t)kv * NN3 + ((c ^ (kv & 15)) << 3), smem + n * 16);
    }
#pragma unroll
    for (int i = 0; i < 4; ++i) {
      int n = i * 256 + t;
      int dr = n >> 3, c = n & 7;
      gload_lds16(Vg + (size_t)dr * SS + ((c ^ (dr & 7)) << 3), smem + 32768 + n * 16);
    }
  }

  for (int kt = 0; kt < 36; ++kt) {
    char* Ksh = smem + (kt & 1) * 16384;
    char* Vsh = smem + 32768 + (kt & 1) * 16384;
    __syncthreads();                     // publish tile kt (loads long in flight)
    if (kt + 1 < 36) {
      const int kv1 = (kt + 1) * 64;
      char* Kn = smem + ((kt + 1) & 1) * 16384;
      char* Vn = smem + 32768 + ((kt + 1) & 1) * 16384;
#pragma unroll
      for (int i = 0; i < 4; ++i) {
        int n = i * 256 + t;
        int kv = n >> 4, c = n & 15;
        gload_lds16(Kg + (size_t)(kv1 + kv) * NN3 + ((c ^ (kv & 15)) << 3), Kn + n * 16);
      }
#pragma unroll
      for (int i = 0; i < 4; ++i) {
        int n = i * 256 + t;
        int dr = n >> 3, c = n & 7;
        gload_lds16(Vg + (size_t)dr * SS + kv1 + ((c ^ (dr & 7)) << 3), Vn + n * 16);
      }
    }

    // S^T tiles: sv[m][kvb][r] = S^T[kappa][q=lq], kappa=(kvb>>1)*32+quad*8+(kvb&1)*4+r
    f32x4 sv[2][4] = {};
#pragma unroll
    for (int kc = 0; kc < 4; ++kc) {
#pragma unroll
      for (int kvb = 0; kvb < 4; ++kvb) {
        int row = ((kvb & 2) << 4) + ((kvb & 1) << 2) + rb;
        int swz = ((kc << 2) | quad) ^ (row & 15);
        frag_u a; a.v = *(const uint4*)(Ksh + row * 256 + swz * 16);
        sv[0][kvb] = __builtin_amdgcn_mfma_f32_16x16x32_bf16(a.f, aq[0][kc].f, sv[0][kvb], 0, 0, 0);
        sv[1][kvb] = __builtin_amdgcn_mfma_f32_16x16x32_bf16(a.f, aq[1][kc].f, sv[1][kvb], 0, 0, 0);
      }
    }

    // P = exp2(S*SC2 - 8), packed straight into PV B-frag dwords. No reductions.
    uint2 pb[2][4];
#pragma unroll
    for (int m = 0; m < 2; ++m) {
#pragma unroll
      for (int kvb = 0; kvb < 4; ++kvb) {
        float p0 = exp2f(fmaf(sv[m][kvb][0], SC2, -8.0f));
        float p1 = exp2f(fmaf(sv[m][kvb][1], SC2, -8.0f));
        float p2 = exp2f(fmaf(sv[m][kvb][2], SC2, -8.0f));
        float p3 = exp2f(fmaf(sv[m][kvb][3], SC2, -8.0f));
        pb[m][kvb].x = pkbf(p0, p1);
        pb[m][kvb].y = pkbf(p2, p3);
      }
    }

    // O^T += V^T P^T ; l += ones . P (same MFMA pipe, same q=lq layout)
#pragma unroll
    for (int kc2 = 0; kc2 < 2; ++kc2) {
      frag_u pf0, pf1;
      pf0.d[0] = pb[0][kc2 * 2].x;     pf0.d[1] = pb[0][kc2 * 2].y;
      pf0.d[2] = pb[0][kc2 * 2 + 1].x; pf0.d[3] = pb[0][kc2 * 2 + 1].y;
      pf1.d[0] = pb[1][kc2 * 2].x;     pf1.d[1] = pb[1][kc2 * 2].y;
      pf1.d[2] = pb[1][kc2 * 2 + 1].x; pf1.d[3] = pb[1][kc2 * 2 + 1].y;
      lacc[0] = __builtin_amdgcn_mfma_f32_16x16x32_bf16(ones.f, pf0.f, lacc[0], 0, 0, 0);
      lacc[1] = __builtin_amdgcn_mfma_f32_16x16x32_bf16(ones.f, pf1.f, lacc[1], 0, 0, 0);
#pragma unroll
      for (int dt = 0; dt < 8; ++dt) {
        int row = dt * 16 + lq;
        int swz = ((kc2 << 2) | quad) ^ (row & 7);
        frag_u a; a.v = *(const uint4*)(Vsh + row * 128 + swz * 16);
        o[0][dt] = __builtin_amdgcn_mfma_f32_16x16x32_bf16(a.f, pf0.f, o[0][dt], 0, 0, 0);
        o[1][dt] = __builtin_amdgcn_mfma_f32_16x16x32_bf16(a.f, pf1.f, o[1][dt], 0, 0, 0);
      }
    }
  }

  // epilogue: O^T -> LDS transpose (swizzled) -> coalesced f32x4 global stores
  __syncthreads();
#pragma unroll
  for (int mch = 0; mch < 2; ++mch) {
    float inv = 1.0f / lacc[mch][0];     // l for q-column lq (all 4 regs identical)
    int row = w * 16 + lq;
#pragma unroll
    for (int dt = 0; dt < 8; ++dt) {
      f32x4 val = o[mch][dt] * inv;
      int swz = ((dt << 2) | quad) ^ (row & 31);
      *(f32x4*)(smem + row * 512 + swz * 16) = val;
    }
    __syncthreads();
#pragma unroll
    for (int i = 0; i < 8; ++i) {
      int n = i * 256 + t;
      int rr = n >> 5, c = n & 31;
      f32x4 v = *(const f32x4*)(smem + rr * 512 + ((c ^ (rr & 31)) << 4));
      int qg = q0 + ((rr >> 4) << 5) + (mch << 4) + (rr & 15);
      *(f32x4*)(out + (size_t)(b * SS + qg) * DD + h * HD + c * 4) = v;
    }
    __syncthreads();
  }
}

// ---------------- launch ------------------------------------------------------
extern "C" void kernel_launch(void* const* d_in, const int* in_sizes, int n_in,
                              void* d_out, int out_size, void* d_ws, size_t ws_size,
                              hipStream_t stream)
{
  const float* hs   = (const float*)d_in[0];
  const float* wqkv = (const float*)d_in[1];
  const float* bq   = (const float*)d_in[2];
  const float* wqn  = (const float*)d_in[3];
  const float* wkn  = (const float*)d_in[4];
  const float* cosb = (const float*)d_in[5];
  const float* sinb = (const float*)d_in[6];
  const int*   tseq = (const int*)d_in[7];
  float* out = (float*)d_out;
  char* ws = (char*)d_ws;

  ushort_t* hsb  = (ushort_t*)ws;                               // 28,311,552 B
  ushort_t* wb   = (ushort_t*)(ws + 28311552);                  // 56,623,104 B
  ushort_t* qkvb = (ushort_t*)(ws + 28311552 + 56623104);       // 84,934,656 B
  ushort_t* vtb  = hsb;                                         // alias (spent after GEMM)

  cvt_bf16_kernel<<<6912, 256, 0, stream>>>(hs, hsb, 1769472);
  cvt_bf16_kernel<<<13824, 256, 0, stream>>>(wqkv, wb, 3538944);
  gemm_qkv_kernel<<<dim3(36, 18), 512, 0, stream>>>(hsb, wb, bq, qkvb);
  norm_rope_kernel<<<27648, 256, 0, stream>>>(qkvb, wqn, wkn, cosb, sinb, tseq);
  vtrans_kernel<<<dim3(36, 48), 256, 0, stream>>>(qkvb, vtb);
  attn_kernel<<<dim3(18, 48), 256, 0, stream>>>(qkvb, vtb, out);
}